// Round 7
// baseline (692.501 us; speedup 1.0000x reference)
//
#include <hip/hip_runtime.h>
#include <math.h>

#define N_NODES  50000
#define N_EDGES  800000
#define HIDDEN   128
#define N_LAYERS 3
#define N_MASKED 25000
#define N_GRAPHS 64
#define NSLICE   8
#define SLICE_F  16   // features per slice

// ordered float<->uint mapping (monotonic): preserves IEEE total order
__device__ __forceinline__ unsigned fmap(float f) {
    unsigned u = __float_as_uint(f);
    return (u & 0x80000000u) ? ~u : (u | 0x80000000u);
}
__device__ __forceinline__ float funmap(unsigned u) {
    return __uint_as_float((u & 0x80000000u) ? (u & 0x7FFFFFFFu) : ~u);
}

// ---------------- degree count (in-degree via dst) ----------------
__global__ void count_deg_kernel(const int* __restrict__ dst, unsigned* __restrict__ deg) {
    int i = blockIdx.x * blockDim.x + threadIdx.x;
    if (i < N_EDGES) atomicAdd(&deg[dst[i]], 1u);
}

__global__ void dinv_kernel(const unsigned* __restrict__ deg, float* __restrict__ dinv) {
    int i = blockIdx.x * blockDim.x + threadIdx.x;
    if (i < N_NODES) dinv[i] = rsqrtf((float)(deg[i] + 1u));   // +1 self-loop
}

// ---------------- prefix sum: per-block inclusive scan ----------------
__global__ void scan_block_kernel(const unsigned* __restrict__ deg, unsigned* __restrict__ incl,
                                  unsigned* __restrict__ bsum) {
    __shared__ unsigned s[1024];
    int i = blockIdx.x * 1024 + threadIdx.x;
    unsigned v = (i < N_NODES) ? deg[i] : 0u;
    s[threadIdx.x] = v;
    __syncthreads();
    for (int off = 1; off < 1024; off <<= 1) {
        unsigned t = (threadIdx.x >= off) ? s[threadIdx.x - off] : 0u;
        __syncthreads();
        s[threadIdx.x] += t;
        __syncthreads();
    }
    if (i < N_NODES) incl[i] = s[threadIdx.x];
    if (threadIdx.x == 1023) bsum[blockIdx.x] = s[1023];
}

__global__ void scan_bsum_kernel(unsigned* __restrict__ bsum, int n) {
    if (blockIdx.x == 0 && threadIdx.x == 0) {
        unsigned run = 0;
        for (int i = 0; i < n; ++i) { unsigned t = bsum[i]; bsum[i] = run; run += t; }
    }
}

__global__ void scan_finalize_kernel(const unsigned* __restrict__ incl,
                                     const unsigned* __restrict__ bsum_ex,
                                     unsigned* __restrict__ row_ptr,
                                     unsigned* __restrict__ cursor) {
    int i = blockIdx.x * blockDim.x + threadIdx.x;
    if (i <= N_NODES) {
        unsigned v = (i == 0) ? 0u : incl[i - 1] + bsum_ex[(i - 1) >> 10];
        row_ptr[i] = v;
        if (i < N_NODES) cursor[i] = v;
    }
}

// ---------------- CSR fill ----------------
__global__ void fill_csr_kernel(const int* __restrict__ src, const int* __restrict__ dst,
                                unsigned* __restrict__ cursor, int* __restrict__ csr_src) {
    int e = blockIdx.x * blockDim.x + threadIdx.x;
    if (e < N_EDGES) {
        unsigned p = atomicAdd(&cursor[dst[e]], 1u);
        csr_src[p] = src[e];
    }
}

// ---------------- GEMM + row-scale, feature-blocked output ----------------
// OutB[slice][r][16] = dinv[r] * (A[r][:] @ W)[slice*16 + 0..15]
__global__ __launch_bounds__(256, 2) void gemm128_kernel(const float* __restrict__ A,
                                                         const float* __restrict__ W,
                                                         const float* __restrict__ dinv,
                                                         float* __restrict__ OutB,
                                                         int nrows) {
    __shared__ float Wl[128 * 128];   // 64 KB
    __shared__ float Rb[32 * 128];    // 16 KB
    const int tid = threadIdx.x;

    for (int i = tid * 4; i < 128 * 128; i += 256 * 4)
        *(float4*)&Wl[i] = *(const float4*)&W[i];
    __syncthreads();

    const int c4 = (tid & 31) * 4;          // col group; slice = c4>>4, f0 = c4&15
    const int rr = tid >> 5;
    const size_t sl_off = (size_t)(c4 >> 4) * ((size_t)N_NODES * SLICE_F) + (c4 & 15);

    for (int rowBase = blockIdx.x * 32; rowBase < nrows; rowBase += gridDim.x * 32) {
        for (int i = tid * 4; i < 32 * 128; i += 256 * 4) {
            int row = rowBase + (i >> 7);
            float4 v = make_float4(0.f, 0.f, 0.f, 0.f);
            if (row < nrows) v = *(const float4*)&A[(size_t)row * 128 + (i & 127)];
            *(float4*)&Rb[i] = v;
        }
        __syncthreads();

        float4 acc[4];
        #pragma unroll
        for (int m = 0; m < 4; ++m) acc[m] = make_float4(0, 0, 0, 0);

        #pragma unroll 4
        for (int k4 = 0; k4 < 128; k4 += 4) {
            float h0[4], h1[4], h2[4], h3[4];
            *(float4*)h0 = *(const float4*)&Rb[(rr +  0) * 128 + k4];
            *(float4*)h1 = *(const float4*)&Rb[(rr +  8) * 128 + k4];
            *(float4*)h2 = *(const float4*)&Rb[(rr + 16) * 128 + k4];
            *(float4*)h3 = *(const float4*)&Rb[(rr + 24) * 128 + k4];
            #pragma unroll
            for (int j = 0; j < 4; ++j) {
                float4 wv = *(const float4*)&Wl[(k4 + j) * 128 + c4];
                acc[0].x += h0[j] * wv.x; acc[0].y += h0[j] * wv.y;
                acc[0].z += h0[j] * wv.z; acc[0].w += h0[j] * wv.w;
                acc[1].x += h1[j] * wv.x; acc[1].y += h1[j] * wv.y;
                acc[1].z += h1[j] * wv.z; acc[1].w += h1[j] * wv.w;
                acc[2].x += h2[j] * wv.x; acc[2].y += h2[j] * wv.y;
                acc[2].z += h2[j] * wv.z; acc[2].w += h2[j] * wv.w;
                acc[3].x += h3[j] * wv.x; acc[3].y += h3[j] * wv.y;
                acc[3].z += h3[j] * wv.z; acc[3].w += h3[j] * wv.w;
            }
        }

        #pragma unroll
        for (int m = 0; m < 4; ++m) {
            int r0 = rowBase + rr + m * 8;
            if (r0 < nrows) {
                float d = dinv[r0];
                float4 o = acc[m];
                o.x *= d; o.y *= d; o.z *= d; o.w *= d;
                *(float4*)&OutB[sl_off + (size_t)r0 * SLICE_F] = o;
            }
        }
        __syncthreads();
    }
}

// ---------------- XCD-sliced CSR gather over blocked rows ----------------
// slice = blockIdx & 7 -> pins each feature slice to one XCD's L2 (3.2 MB table).
// Wave handles one (item, slice): 16 lanes/feature x 4 edge groups, 2-deep chains.
__global__ __launch_bounds__(256) void gather_kernel(const float* __restrict__ hwsB,
                                                     const unsigned* __restrict__ row_ptr,
                                                     const int* __restrict__ csr_src,
                                                     const float* __restrict__ dinv,
                                                     const float* __restrict__ bias,
                                                     float* __restrict__ out,
                                                     const int* __restrict__ nodes,
                                                     const int* __restrict__ batch,
                                                     unsigned* __restrict__ gmax,
                                                     int n_items) {
    const int b = blockIdx.x;
    const int s = b & 7;
    const int w = (b >> 3) * 4 + (threadIdx.x >> 6);
    if (w >= n_items) return;
    const int lane = threadIdx.x & 63;
    const int f = lane & 15;
    const int g = lane >> 4;   // edge group 0..3
    const int v = nodes ? nodes[w] : w;

    const float* __restrict__ tab = hwsB + (size_t)s * ((size_t)N_NODES * SLICE_F) + f;

    const unsigned s0 = row_ptr[v], e0 = row_ptr[v + 1];
    float acc0 = (g == 0) ? tab[(size_t)v * SLICE_F] : 0.f;   // self-loop row
    float acc1 = 0.f;

    unsigned i = s0 + g;
    for (; i + 8 <= e0; i += 8) {          // 8 edges in flight per wave
        int iA = csr_src[i];
        int iB = csr_src[i + 4];
        acc0 += tab[(size_t)iA * SLICE_F];
        acc1 += tab[(size_t)iB * SLICE_F];
    }
    for (; i < e0; i += 4)
        acc0 += tab[(size_t)csr_src[i] * SLICE_F];

    float val = acc0 + acc1;
    val += __shfl_down(val, 32);
    val += __shfl_down(val, 16);           // lanes 0..15 hold slice sums

    if (lane < 16) {
        float o = dinv[v] * val + bias[s * SLICE_F + f];
        o = o > 0.f ? o : expm1f(o);
        if (gmax) atomicMax(&gmax[batch[w] * 128 + s * SLICE_F + f], fmap(o));
        else      out[(size_t)w * 128 + s * SLICE_F + f] = o;
    }
}

// ---------------- init gmax to mapped(-inf) ----------------
__global__ void gmax_init_kernel(unsigned* __restrict__ gmax) {
    int i = blockIdx.x * blockDim.x + threadIdx.x;
    if (i < N_GRAPHS * 128) gmax[i] = 0x007FFFFFu;  // fmap(-inf)
}

// ---------------- finish: out[g] = sum_f unmap(gmax[g][f]) * w[f] + b ----------------
__global__ void pool_finish_kernel(const unsigned* __restrict__ gmax,
                                   const float* __restrict__ w, const float* __restrict__ b,
                                   float* __restrict__ out) {
    const int g = blockIdx.x;
    const int f = threadIdx.x;
    float val = funmap(gmax[g * 128 + f]) * w[f];
    #pragma unroll
    for (int off = 32; off > 0; off >>= 1) val += __shfl_down(val, off);
    __shared__ float ps[2];
    if ((threadIdx.x & 63) == 0) ps[threadIdx.x >> 6] = val;
    __syncthreads();
    if (threadIdx.x == 0) out[g] = ps[0] + ps[1] + b[0];
}

extern "C" void kernel_launch(void* const* d_in, const int* in_sizes, int n_in,
                              void* d_out, int out_size, void* d_ws, size_t ws_size,
                              hipStream_t stream) {
    const float* x      = (const float*)d_in[0];
    const int*   ei     = (const int*)d_in[1];
    const int*   mask   = (const int*)d_in[2];
    const int*   batch  = (const int*)d_in[3];
    const float* conv_w = (const float*)d_in[4];
    const float* conv_b = (const float*)d_in[5];
    const float* lt1_w  = (const float*)d_in[6];
    const float* lt1_b  = (const float*)d_in[7];
    float* out = (float*)d_out;

    const int* e_src = ei;
    const int* e_dst = ei + N_EDGES;

    // ---- workspace carve-up (aligned to 256B) ----
    char* ws = (char*)d_ws;
    auto carve = [&](size_t bytes) { char* p = ws; ws += (bytes + 255) & ~(size_t)255; return p; };
    unsigned* deg     = (unsigned*)carve(N_NODES * 4);
    float*    dinv    = (float*)   carve(N_NODES * 4);
    unsigned* row_ptr = (unsigned*)carve((N_NODES + 1) * 4);
    unsigned* cursor  = (unsigned*)carve(N_NODES * 4);
    unsigned* bsum    = (unsigned*)carve(64 * 4);
    unsigned* gmax    = (unsigned*)carve(N_GRAPHS * 128 * 4);
    int*      csr_src = (int*)     carve((size_t)N_EDGES * 4);
    float*    hws     = (float*)   carve((size_t)N_NODES * HIDDEN * 4);  // blocked [8][N][16]
    float*    hbuf    = (float*)   carve((size_t)N_NODES * HIDDEN * 4);  // row-major
    unsigned* incl    = (unsigned*)csr_src;  // alias: dead before fill_csr runs

    const int NB_SCAN = (N_NODES + 1023) / 1024;  // 49

    // ---- build dinv + CSR ----
    hipMemsetAsync(deg, 0, N_NODES * sizeof(unsigned), stream);
    count_deg_kernel<<<(N_EDGES + 255) / 256, 256, 0, stream>>>(e_dst, deg);
    dinv_kernel<<<(N_NODES + 255) / 256, 256, 0, stream>>>(deg, dinv);
    scan_block_kernel<<<NB_SCAN, 1024, 0, stream>>>(deg, incl, bsum);
    scan_bsum_kernel<<<1, 64, 0, stream>>>(bsum, NB_SCAN);
    scan_finalize_kernel<<<(N_NODES + 256) / 256, 256, 0, stream>>>(incl, bsum, row_ptr, cursor);
    fill_csr_kernel<<<(N_EDGES + 255) / 256, 256, 0, stream>>>(e_src, e_dst, cursor, csr_src);
    gmax_init_kernel<<<(N_GRAPHS * 128 + 255) / 256, 256, 0, stream>>>(gmax);

    // ---- 3 GCN layers ----
    const float* h_in = x;
    for (int l = 0; l < N_LAYERS; ++l) {
        gemm128_kernel<<<512, 256, 0, stream>>>(h_in, conv_w + l * 128 * 128, dinv, hws, N_NODES);
        if (l < N_LAYERS - 1) {
            // blocks = 8 slices x ceil(N/4) node groups
            gather_kernel<<<NSLICE * ((N_NODES + 3) / 4), 256, 0, stream>>>(
                hws, row_ptr, csr_src, dinv, conv_b + l * HIDDEN, hbuf,
                nullptr, nullptr, nullptr, N_NODES);
            h_in = hbuf;
        } else {
            gather_kernel<<<NSLICE * ((N_MASKED + 3) / 4), 256, 0, stream>>>(
                hws, row_ptr, csr_src, dinv, conv_b + l * HIDDEN, nullptr,
                mask, batch, gmax, N_MASKED);
        }
    }

    pool_finish_kernel<<<N_GRAPHS, HIDDEN, 0, stream>>>(gmax, lt1_w, lt1_b, out);
}

// Round 8
// 405.985 us; speedup vs baseline: 1.7057x; 1.7057x over previous
//
#include <hip/hip_runtime.h>
#include <math.h>

#define N_NODES  50000
#define N_EDGES  800000
#define HIDDEN   128
#define N_LAYERS 3
#define N_MASKED 25000
#define N_GRAPHS 64

// ordered float<->uint mapping (monotonic): preserves IEEE total order
__device__ __forceinline__ unsigned fmap(float f) {
    unsigned u = __float_as_uint(f);
    return (u & 0x80000000u) ? ~u : (u | 0x80000000u);
}
__device__ __forceinline__ float funmap(unsigned u) {
    return __uint_as_float((u & 0x80000000u) ? (u & 0x7FFFFFFFu) : ~u);
}

// ---------------- degree count (in-degree via dst) ----------------
__global__ void count_deg_kernel(const int* __restrict__ dst, unsigned* __restrict__ deg) {
    int i = blockIdx.x * blockDim.x + threadIdx.x;
    if (i < N_EDGES) atomicAdd(&deg[dst[i]], 1u);
}

__global__ void dinv_kernel(const unsigned* __restrict__ deg, float* __restrict__ dinv) {
    int i = blockIdx.x * blockDim.x + threadIdx.x;
    if (i < N_NODES) dinv[i] = rsqrtf((float)(deg[i] + 1u));   // +1 self-loop
}

// ---------------- prefix sum: per-block inclusive scan ----------------
__global__ void scan_block_kernel(const unsigned* __restrict__ deg, unsigned* __restrict__ incl,
                                  unsigned* __restrict__ bsum) {
    __shared__ unsigned s[1024];
    int i = blockIdx.x * 1024 + threadIdx.x;
    unsigned v = (i < N_NODES) ? deg[i] : 0u;
    s[threadIdx.x] = v;
    __syncthreads();
    for (int off = 1; off < 1024; off <<= 1) {
        unsigned t = (threadIdx.x >= off) ? s[threadIdx.x - off] : 0u;
        __syncthreads();
        s[threadIdx.x] += t;
        __syncthreads();
    }
    if (i < N_NODES) incl[i] = s[threadIdx.x];
    if (threadIdx.x == 1023) bsum[blockIdx.x] = s[1023];
}

__global__ void scan_bsum_kernel(unsigned* __restrict__ bsum, int n) {
    if (blockIdx.x == 0 && threadIdx.x == 0) {
        unsigned run = 0;
        for (int i = 0; i < n; ++i) { unsigned t = bsum[i]; bsum[i] = run; run += t; }
    }
}

__global__ void scan_finalize_kernel(const unsigned* __restrict__ incl,
                                     const unsigned* __restrict__ bsum_ex,
                                     unsigned* __restrict__ row_ptr,
                                     unsigned* __restrict__ cursor) {
    int i = blockIdx.x * blockDim.x + threadIdx.x;
    if (i <= N_NODES) {
        unsigned v = (i == 0) ? 0u : incl[i - 1] + bsum_ex[(i - 1) >> 10];
        row_ptr[i] = v;
        if (i < N_NODES) cursor[i] = v;
    }
}

// ---------------- CSR fill ----------------
__global__ void fill_csr_kernel(const int* __restrict__ src, const int* __restrict__ dst,
                                unsigned* __restrict__ cursor, int* __restrict__ csr_src) {
    int e = blockIdx.x * blockDim.x + threadIdx.x;
    if (e < N_EDGES) {
        unsigned p = atomicAdd(&cursor[dst[e]], 1u);
        csr_src[p] = src[e];
    }
}

// ---------------- GEMM + row-scale: Out[r][:] = dinv[r] * (A[r][:] @ W) ----------------
// W read straight from global: 64 KB, L2-resident, lanes 32-63 mirror lanes
// 0-31's addresses (broadcast) -> cheap. LDS holds only the 32-row A tile
// (16 KB) -> ~10 blocks/CU, 8 waves/SIMD instead of 2.
__global__ __launch_bounds__(256) void gemm128_kernel(const float* __restrict__ A,
                                                      const float* __restrict__ W,
                                                      const float* __restrict__ dinv,
                                                      float* __restrict__ Out,
                                                      int nrows) {
    __shared__ float Rb[32 * 128];    // 16 KB
    const int tid = threadIdx.x;
    const int c4 = (tid & 31) * 4;
    const int rr = tid >> 5;
    const int rowBase = blockIdx.x * 32;
    if (rowBase >= nrows) return;

    for (int i = tid * 4; i < 32 * 128; i += 256 * 4) {
        int row = rowBase + (i >> 7);
        float4 v = make_float4(0.f, 0.f, 0.f, 0.f);
        if (row < nrows) v = *(const float4*)&A[(size_t)row * 128 + (i & 127)];
        *(float4*)&Rb[i] = v;
    }
    __syncthreads();

    float4 acc[4];
    #pragma unroll
    for (int m = 0; m < 4; ++m) acc[m] = make_float4(0, 0, 0, 0);

    #pragma unroll 2
    for (int k4 = 0; k4 < 128; k4 += 4) {
        float4 wv[4];
        #pragma unroll
        for (int j = 0; j < 4; ++j)
            wv[j] = *(const float4*)&W[(size_t)(k4 + j) * 128 + c4];

        float h0[4], h1[4], h2[4], h3[4];
        *(float4*)h0 = *(const float4*)&Rb[(rr +  0) * 128 + k4];
        *(float4*)h1 = *(const float4*)&Rb[(rr +  8) * 128 + k4];
        *(float4*)h2 = *(const float4*)&Rb[(rr + 16) * 128 + k4];
        *(float4*)h3 = *(const float4*)&Rb[(rr + 24) * 128 + k4];

        #pragma unroll
        for (int j = 0; j < 4; ++j) {
            acc[0].x += h0[j] * wv[j].x; acc[0].y += h0[j] * wv[j].y;
            acc[0].z += h0[j] * wv[j].z; acc[0].w += h0[j] * wv[j].w;
            acc[1].x += h1[j] * wv[j].x; acc[1].y += h1[j] * wv[j].y;
            acc[1].z += h1[j] * wv[j].z; acc[1].w += h1[j] * wv[j].w;
            acc[2].x += h2[j] * wv[j].x; acc[2].y += h2[j] * wv[j].y;
            acc[2].z += h2[j] * wv[j].z; acc[2].w += h2[j] * wv[j].w;
            acc[3].x += h3[j] * wv[j].x; acc[3].y += h3[j] * wv[j].y;
            acc[3].z += h3[j] * wv[j].z; acc[3].w += h3[j] * wv[j].w;
        }
    }

    #pragma unroll
    for (int m = 0; m < 4; ++m) {
        int r0 = rowBase + rr + m * 8;
        if (r0 < nrows) {
            float d = dinv[r0];
            float4 o = acc[m];
            o.x *= d; o.y *= d; o.z *= d; o.w *= d;
            *(float4*)&Out[(size_t)r0 * 128 + c4] = o;
        }
    }
}

// ---------------- CSR gather over pre-scaled rows (round-5 shape) ----------------
// wave wid -> (item w = wid>>1, half = wid&1); lane covers one feature.
// 8 independent accumulator chains, group-prefetched indices.
__global__ __launch_bounds__(256) void gather_kernel(const float* __restrict__ hws,
                                                     const unsigned* __restrict__ row_ptr,
                                                     const int* __restrict__ csr_src,
                                                     const float* __restrict__ dinv,
                                                     const float* __restrict__ bias,
                                                     float* __restrict__ out,
                                                     const int* __restrict__ nodes,
                                                     const int* __restrict__ batch,
                                                     unsigned* __restrict__ gmax,
                                                     int n_items) {
    int wid = (blockIdx.x * blockDim.x + threadIdx.x) >> 6;
    int w = wid >> 1;
    if (w >= n_items) return;
    const int f = ((wid & 1) << 6) | (threadIdx.x & 63);
    const int v = nodes ? nodes[w] : w;

    const unsigned s0 = row_ptr[v], e0 = row_ptr[v + 1];
    const float* __restrict__ base = hws + f;

    float acc[8];
    #pragma unroll
    for (int j = 0; j < 8; ++j) acc[j] = 0.f;
    acc[0] = base[(size_t)v << 7];   // self-loop row

    unsigned i = s0;
    if (i + 8 <= e0) {
        int idx[8];
        #pragma unroll
        for (int j = 0; j < 8; ++j) idx[j] = csr_src[i + j];
        for (; i + 16 <= e0; i += 8) {
            int nxt[8];
            #pragma unroll
            for (int j = 0; j < 8; ++j) nxt[j] = csr_src[i + 8 + j];
            #pragma unroll
            for (int j = 0; j < 8; ++j) acc[j] += base[(size_t)idx[j] << 7];
            #pragma unroll
            for (int j = 0; j < 8; ++j) idx[j] = nxt[j];
        }
        #pragma unroll
        for (int j = 0; j < 8; ++j) acc[j] += base[(size_t)idx[j] << 7];
        i += 8;
    }
    if (i + 4 <= e0) {
        #pragma unroll
        for (int j = 0; j < 4; ++j) acc[j] += base[(size_t)csr_src[i + j] << 7];
        i += 4;
    }
    for (; i < e0; ++i) acc[0] += base[(size_t)csr_src[i] << 7];

    float o = dinv[v] * (((acc[0] + acc[1]) + (acc[2] + acc[3])) +
                         ((acc[4] + acc[5]) + (acc[6] + acc[7]))) + bias[f];
    o = o > 0.f ? o : expm1f(o);

    if (gmax) {
        atomicMax(&gmax[batch[w] * 128 + f], fmap(o));
    } else {
        out[((size_t)w << 7) + f] = o;
    }
}

// ---------------- init gmax to mapped(-inf) ----------------
__global__ void gmax_init_kernel(unsigned* __restrict__ gmax) {
    int i = blockIdx.x * blockDim.x + threadIdx.x;
    if (i < N_GRAPHS * 128) gmax[i] = 0x007FFFFFu;  // fmap(-inf)
}

// ---------------- finish: out[g] = sum_f unmap(gmax[g][f]) * w[f] + b ----------------
__global__ void pool_finish_kernel(const unsigned* __restrict__ gmax,
                                   const float* __restrict__ w, const float* __restrict__ b,
                                   float* __restrict__ out) {
    const int g = blockIdx.x;
    const int f = threadIdx.x;
    float val = funmap(gmax[g * 128 + f]) * w[f];
    #pragma unroll
    for (int off = 32; off > 0; off >>= 1) val += __shfl_down(val, off);
    __shared__ float ps[2];
    if ((threadIdx.x & 63) == 0) ps[threadIdx.x >> 6] = val;
    __syncthreads();
    if (threadIdx.x == 0) out[g] = ps[0] + ps[1] + b[0];
}

extern "C" void kernel_launch(void* const* d_in, const int* in_sizes, int n_in,
                              void* d_out, int out_size, void* d_ws, size_t ws_size,
                              hipStream_t stream) {
    const float* x      = (const float*)d_in[0];
    const int*   ei     = (const int*)d_in[1];
    const int*   mask   = (const int*)d_in[2];
    const int*   batch  = (const int*)d_in[3];
    const float* conv_w = (const float*)d_in[4];
    const float* conv_b = (const float*)d_in[5];
    const float* lt1_w  = (const float*)d_in[6];
    const float* lt1_b  = (const float*)d_in[7];
    float* out = (float*)d_out;

    const int* e_src = ei;
    const int* e_dst = ei + N_EDGES;

    // ---- workspace carve-up (aligned to 256B) ----
    char* ws = (char*)d_ws;
    auto carve = [&](size_t bytes) { char* p = ws; ws += (bytes + 255) & ~(size_t)255; return p; };
    unsigned* deg     = (unsigned*)carve(N_NODES * 4);
    float*    dinv    = (float*)   carve(N_NODES * 4);
    unsigned* row_ptr = (unsigned*)carve((N_NODES + 1) * 4);
    unsigned* cursor  = (unsigned*)carve(N_NODES * 4);
    unsigned* bsum    = (unsigned*)carve(64 * 4);
    unsigned* gmax    = (unsigned*)carve(N_GRAPHS * 128 * 4);
    int*      csr_src = (int*)     carve((size_t)N_EDGES * 4);
    float*    hws     = (float*)   carve((size_t)N_NODES * HIDDEN * 4);
    float*    hbuf    = (float*)   carve((size_t)N_NODES * HIDDEN * 4);
    unsigned* incl    = (unsigned*)csr_src;  // alias: dead before fill_csr runs

    const int NB_SCAN = (N_NODES + 1023) / 1024;  // 49

    // ---- build dinv + CSR ----
    hipMemsetAsync(deg, 0, N_NODES * sizeof(unsigned), stream);
    count_deg_kernel<<<(N_EDGES + 255) / 256, 256, 0, stream>>>(e_dst, deg);
    dinv_kernel<<<(N_NODES + 255) / 256, 256, 0, stream>>>(deg, dinv);
    scan_block_kernel<<<NB_SCAN, 1024, 0, stream>>>(deg, incl, bsum);
    scan_bsum_kernel<<<1, 64, 0, stream>>>(bsum, NB_SCAN);
    scan_finalize_kernel<<<(N_NODES + 256) / 256, 256, 0, stream>>>(incl, bsum, row_ptr, cursor);
    fill_csr_kernel<<<(N_EDGES + 255) / 256, 256, 0, stream>>>(e_src, e_dst, cursor, csr_src);
    gmax_init_kernel<<<(N_GRAPHS * 128 + 255) / 256, 256, 0, stream>>>(gmax);

    // ---- 3 GCN layers ----
    const float* h_in = x;
    for (int l = 0; l < N_LAYERS; ++l) {
        gemm128_kernel<<<(N_NODES + 31) / 32, 256, 0, stream>>>(
            h_in, conv_w + l * 128 * 128, dinv, hws, N_NODES);
        if (l < N_LAYERS - 1) {
            gather_kernel<<<(N_NODES * 2 * 64 + 255) / 256, 256, 0, stream>>>(
                hws, row_ptr, csr_src, dinv, conv_b + l * HIDDEN, hbuf,
                nullptr, nullptr, nullptr, N_NODES);
            h_in = hbuf;
        } else {
            gather_kernel<<<(N_MASKED * 2 * 64 + 255) / 256, 256, 0, stream>>>(
                hws, row_ptr, csr_src, dinv, conv_b + l * HIDDEN, nullptr,
                mask, batch, gmax, N_MASKED);
        }
    }

    pool_finish_kernel<<<N_GRAPHS, HIDDEN, 0, stream>>>(gmax, lt1_w, lt1_b, out);
}

// Round 9
// 401.715 us; speedup vs baseline: 1.7239x; 1.0106x over previous
//
#include <hip/hip_runtime.h>
#include <math.h>

#define N_NODES  50000
#define N_EDGES  800000
#define HIDDEN   128
#define N_LAYERS 3
#define N_MASKED 25000
#define N_GRAPHS 64

// ordered float<->uint mapping (monotonic): preserves IEEE total order
__device__ __forceinline__ unsigned fmap(float f) {
    unsigned u = __float_as_uint(f);
    return (u & 0x80000000u) ? ~u : (u | 0x80000000u);
}
__device__ __forceinline__ float funmap(unsigned u) {
    return __uint_as_float((u & 0x80000000u) ? (u & 0x7FFFFFFFu) : ~u);
}

// ---------------- degree count (in-degree via dst) ----------------
__global__ void count_deg_kernel(const int* __restrict__ dst, unsigned* __restrict__ deg) {
    int i = blockIdx.x * blockDim.x + threadIdx.x;
    if (i < N_EDGES) atomicAdd(&deg[dst[i]], 1u);
}

__global__ void dinv_kernel(const unsigned* __restrict__ deg, float* __restrict__ dinv) {
    int i = blockIdx.x * blockDim.x + threadIdx.x;
    if (i < N_NODES) dinv[i] = rsqrtf((float)(deg[i] + 1u));   // +1 self-loop
}

// ---------------- prefix sum: per-block inclusive scan ----------------
__global__ void scan_block_kernel(const unsigned* __restrict__ deg, unsigned* __restrict__ incl,
                                  unsigned* __restrict__ bsum) {
    __shared__ unsigned s[1024];
    int i = blockIdx.x * 1024 + threadIdx.x;
    unsigned v = (i < N_NODES) ? deg[i] : 0u;
    s[threadIdx.x] = v;
    __syncthreads();
    for (int off = 1; off < 1024; off <<= 1) {
        unsigned t = (threadIdx.x >= off) ? s[threadIdx.x - off] : 0u;
        __syncthreads();
        s[threadIdx.x] += t;
        __syncthreads();
    }
    if (i < N_NODES) incl[i] = s[threadIdx.x];
    if (threadIdx.x == 1023) bsum[blockIdx.x] = s[1023];
}

__global__ void scan_bsum_kernel(unsigned* __restrict__ bsum, int n) {
    if (blockIdx.x == 0 && threadIdx.x == 0) {
        unsigned run = 0;
        for (int i = 0; i < n; ++i) { unsigned t = bsum[i]; bsum[i] = run; run += t; }
    }
}

__global__ void scan_finalize_kernel(const unsigned* __restrict__ incl,
                                     const unsigned* __restrict__ bsum_ex,
                                     unsigned* __restrict__ row_ptr,
                                     unsigned* __restrict__ cursor) {
    int i = blockIdx.x * blockDim.x + threadIdx.x;
    if (i <= N_NODES) {
        unsigned v = (i == 0) ? 0u : incl[i - 1] + bsum_ex[(i - 1) >> 10];
        row_ptr[i] = v;
        if (i < N_NODES) cursor[i] = v;
    }
}

// ---------------- CSR fill ----------------
__global__ void fill_csr_kernel(const int* __restrict__ src, const int* __restrict__ dst,
                                unsigned* __restrict__ cursor, int* __restrict__ csr_src) {
    int e = blockIdx.x * blockDim.x + threadIdx.x;
    if (e < N_EDGES) {
        unsigned p = atomicAdd(&cursor[dst[e]], 1u);
        csr_src[p] = src[e];
    }
}

// ---------------- GEMM + row-scale: Out[r][:] = dinv[r] * (A[r][:] @ W) ----------------
// Column-split: each block does 32 rows x 64 cols. W-slice (32 KB) + padded
// A-tile (16.5 KB) = 48.5 KB LDS -> 3 blocks/CU, 12 waves/CU (vs 2 blk/8 w).
// Per thread: 2 rows x 4 cols. Per-k LDS 24 B/lane (12 clk) < 16 FMA cyc.
#define ASTRIDE 132   // 128 + 4 pad: rr*132 mod 32 spreads banks
__global__ __launch_bounds__(256) void gemm128_kernel(const float* __restrict__ A,
                                                      const float* __restrict__ W,
                                                      const float* __restrict__ dinv,
                                                      float* __restrict__ Out,
                                                      int nrows) {
    __shared__ float Wl[128 * 64];      // 32 KB, k-major slice
    __shared__ float Rb[32 * ASTRIDE];  // 16.5 KB
    const int tid = threadIdx.x;
    const int rowBase = (blockIdx.x >> 1) * 32;
    const int colHalf = (blockIdx.x & 1) * 64;
    if (rowBase >= nrows) return;

    // stage W-slice: Wl[k][c] = W[k][colHalf + c]
    for (int i = tid * 4; i < 128 * 64; i += 256 * 4) {
        int k = i >> 6, c = i & 63;
        *(float4*)&Wl[i] = *(const float4*)&W[(size_t)k * 128 + colHalf + c];
    }
    // stage A-tile (padded stride)
    for (int i = tid * 4; i < 32 * 128; i += 256 * 4) {
        int r = i >> 7, col = i & 127;
        int row = rowBase + r;
        float4 v = make_float4(0.f, 0.f, 0.f, 0.f);
        if (row < nrows) v = *(const float4*)&A[(size_t)row * 128 + col];
        *(float4*)&Rb[r * ASTRIDE + col] = v;
    }
    __syncthreads();

    const int c4 = (tid & 15) * 4;   // col group within 64
    const int rr = tid >> 4;         // row slot 0..15; rows rr, rr+16

    float4 acc0 = make_float4(0, 0, 0, 0), acc1 = make_float4(0, 0, 0, 0);

    #pragma unroll 4
    for (int k4 = 0; k4 < 128; k4 += 4) {
        float h0[4], h1[4];
        *(float4*)h0 = *(const float4*)&Rb[rr * ASTRIDE + k4];
        *(float4*)h1 = *(const float4*)&Rb[(rr + 16) * ASTRIDE + k4];
        #pragma unroll
        for (int j = 0; j < 4; ++j) {
            float4 wv = *(const float4*)&Wl[(k4 + j) * 64 + c4];
            acc0.x += h0[j] * wv.x; acc0.y += h0[j] * wv.y;
            acc0.z += h0[j] * wv.z; acc0.w += h0[j] * wv.w;
            acc1.x += h1[j] * wv.x; acc1.y += h1[j] * wv.y;
            acc1.z += h1[j] * wv.z; acc1.w += h1[j] * wv.w;
        }
    }

    int r0 = rowBase + rr;
    if (r0 < nrows) {
        float d = dinv[r0];
        acc0.x *= d; acc0.y *= d; acc0.z *= d; acc0.w *= d;
        *(float4*)&Out[(size_t)r0 * 128 + colHalf + c4] = acc0;
    }
    if (r0 + 16 < nrows) {
        float d = dinv[r0 + 16];
        acc1.x *= d; acc1.y *= d; acc1.z *= d; acc1.w *= d;
        *(float4*)&Out[(size_t)(r0 + 16) * 128 + colHalf + c4] = acc1;
    }
}

// ---------------- CSR gather over pre-scaled rows (round-5 shape) ----------------
__global__ __launch_bounds__(256) void gather_kernel(const float* __restrict__ hws,
                                                     const unsigned* __restrict__ row_ptr,
                                                     const int* __restrict__ csr_src,
                                                     const float* __restrict__ dinv,
                                                     const float* __restrict__ bias,
                                                     float* __restrict__ out,
                                                     const int* __restrict__ nodes,
                                                     const int* __restrict__ batch,
                                                     unsigned* __restrict__ gmax,
                                                     int n_items) {
    int wid = (blockIdx.x * blockDim.x + threadIdx.x) >> 6;
    int w = wid >> 1;
    if (w >= n_items) return;
    const int f = ((wid & 1) << 6) | (threadIdx.x & 63);
    const int v = nodes ? nodes[w] : w;

    const unsigned s0 = row_ptr[v], e0 = row_ptr[v + 1];
    const float* __restrict__ base = hws + f;

    float acc[8];
    #pragma unroll
    for (int j = 0; j < 8; ++j) acc[j] = 0.f;
    acc[0] = base[(size_t)v << 7];   // self-loop row

    unsigned i = s0;
    if (i + 8 <= e0) {
        int idx[8];
        #pragma unroll
        for (int j = 0; j < 8; ++j) idx[j] = csr_src[i + j];
        for (; i + 16 <= e0; i += 8) {
            int nxt[8];
            #pragma unroll
            for (int j = 0; j < 8; ++j) nxt[j] = csr_src[i + 8 + j];
            #pragma unroll
            for (int j = 0; j < 8; ++j) acc[j] += base[(size_t)idx[j] << 7];
            #pragma unroll
            for (int j = 0; j < 8; ++j) idx[j] = nxt[j];
        }
        #pragma unroll
        for (int j = 0; j < 8; ++j) acc[j] += base[(size_t)idx[j] << 7];
        i += 8;
    }
    if (i + 4 <= e0) {
        #pragma unroll
        for (int j = 0; j < 4; ++j) acc[j] += base[(size_t)csr_src[i + j] << 7];
        i += 4;
    }
    for (; i < e0; ++i) acc[0] += base[(size_t)csr_src[i] << 7];

    float o = dinv[v] * (((acc[0] + acc[1]) + (acc[2] + acc[3])) +
                         ((acc[4] + acc[5]) + (acc[6] + acc[7]))) + bias[f];
    o = o > 0.f ? o : expm1f(o);

    if (gmax) {
        atomicMax(&gmax[batch[w] * 128 + f], fmap(o));
    } else {
        out[((size_t)w << 7) + f] = o;
    }
}

// ---------------- init gmax to mapped(-inf) ----------------
__global__ void gmax_init_kernel(unsigned* __restrict__ gmax) {
    int i = blockIdx.x * blockDim.x + threadIdx.x;
    if (i < N_GRAPHS * 128) gmax[i] = 0x007FFFFFu;  // fmap(-inf)
}

// ---------------- finish: out[g] = sum_f unmap(gmax[g][f]) * w[f] + b ----------------
__global__ void pool_finish_kernel(const unsigned* __restrict__ gmax,
                                   const float* __restrict__ w, const float* __restrict__ b,
                                   float* __restrict__ out) {
    const int g = blockIdx.x;
    const int f = threadIdx.x;
    float val = funmap(gmax[g * 128 + f]) * w[f];
    #pragma unroll
    for (int off = 32; off > 0; off >>= 1) val += __shfl_down(val, off);
    __shared__ float ps[2];
    if ((threadIdx.x & 63) == 0) ps[threadIdx.x >> 6] = val;
    __syncthreads();
    if (threadIdx.x == 0) out[g] = ps[0] + ps[1] + b[0];
}

extern "C" void kernel_launch(void* const* d_in, const int* in_sizes, int n_in,
                              void* d_out, int out_size, void* d_ws, size_t ws_size,
                              hipStream_t stream) {
    const float* x      = (const float*)d_in[0];
    const int*   ei     = (const int*)d_in[1];
    const int*   mask   = (const int*)d_in[2];
    const int*   batch  = (const int*)d_in[3];
    const float* conv_w = (const float*)d_in[4];
    const float* conv_b = (const float*)d_in[5];
    const float* lt1_w  = (const float*)d_in[6];
    const float* lt1_b  = (const float*)d_in[7];
    float* out = (float*)d_out;

    const int* e_src = ei;
    const int* e_dst = ei + N_EDGES;

    // ---- workspace carve-up (aligned to 256B) ----
    char* ws = (char*)d_ws;
    auto carve = [&](size_t bytes) { char* p = ws; ws += (bytes + 255) & ~(size_t)255; return p; };
    unsigned* deg     = (unsigned*)carve(N_NODES * 4);
    float*    dinv    = (float*)   carve(N_NODES * 4);
    unsigned* row_ptr = (unsigned*)carve((N_NODES + 1) * 4);
    unsigned* cursor  = (unsigned*)carve(N_NODES * 4);
    unsigned* bsum    = (unsigned*)carve(64 * 4);
    unsigned* gmax    = (unsigned*)carve(N_GRAPHS * 128 * 4);
    int*      csr_src = (int*)     carve((size_t)N_EDGES * 4);
    float*    hws     = (float*)   carve((size_t)N_NODES * HIDDEN * 4);
    float*    hbuf    = (float*)   carve((size_t)N_NODES * HIDDEN * 4);
    unsigned* incl    = (unsigned*)csr_src;  // alias: dead before fill_csr runs

    const int NB_SCAN = (N_NODES + 1023) / 1024;  // 49

    // ---- build dinv + CSR ----
    hipMemsetAsync(deg, 0, N_NODES * sizeof(unsigned), stream);
    count_deg_kernel<<<(N_EDGES + 255) / 256, 256, 0, stream>>>(e_dst, deg);
    dinv_kernel<<<(N_NODES + 255) / 256, 256, 0, stream>>>(deg, dinv);
    scan_block_kernel<<<NB_SCAN, 1024, 0, stream>>>(deg, incl, bsum);
    scan_bsum_kernel<<<1, 64, 0, stream>>>(bsum, NB_SCAN);
    scan_finalize_kernel<<<(N_NODES + 256) / 256, 256, 0, stream>>>(incl, bsum, row_ptr, cursor);
    fill_csr_kernel<<<(N_EDGES + 255) / 256, 256, 0, stream>>>(e_src, e_dst, cursor, csr_src);
    gmax_init_kernel<<<(N_GRAPHS * 128 + 255) / 256, 256, 0, stream>>>(gmax);

    // ---- 3 GCN layers ----
    const int NGEMM_BLK = ((N_NODES + 31) / 32) * 2;   // row-tiles x 2 col-halves
    const float* h_in = x;
    for (int l = 0; l < N_LAYERS; ++l) {
        gemm128_kernel<<<NGEMM_BLK, 256, 0, stream>>>(
            h_in, conv_w + l * 128 * 128, dinv, hws, N_NODES);
        if (l < N_LAYERS - 1) {
            gather_kernel<<<(N_NODES * 2 * 64 + 255) / 256, 256, 0, stream>>>(
                hws, row_ptr, csr_src, dinv, conv_b + l * HIDDEN, hbuf,
                nullptr, nullptr, nullptr, N_NODES);
            h_in = hbuf;
        } else {
            gather_kernel<<<(N_MASKED * 2 * 64 + 255) / 256, 256, 0, stream>>>(
                hws, row_ptr, csr_src, dinv, conv_b + l * HIDDEN, nullptr,
                mask, batch, gmax, N_MASKED);
        }
    }

    pool_finish_kernel<<<N_GRAPHS, HIDDEN, 0, stream>>>(gmax, lt1_w, lt1_b, out);
}